// Round 5
// baseline (2243.033 us; speedup 1.0000x reference)
//
#include <hip/hip_runtime.h>

// ---------------------------------------------------------------------------
// unit_gcn: out[n,o,t,v] = BN+ReLU of  sum_{s=0..24} Ws[s] @_c x[n,:,t,(v+s)%25]
//   Ws[0] = sum_i W[i,:,:,0];  Ws[s] = W[s-1,:,:,1]  (s>=1); bias cancels in BN.
// N=64, C=64, T=300, V=25, O=64.  x fp32 -> bf16 MFMA (16x16x32), fp32 accum.
// K split into two 32-c chunk passes -> 27.2KB A-slab -> 5 blocks/CU (occupancy).
// ---------------------------------------------------------------------------

typedef short  s16x8 __attribute__((ext_vector_type(8)));
typedef float  f32x4 __attribute__((ext_vector_type(4)));

#define T_      300
#define TB_     19          // ceil(300/16) t-blocks
#define NTHR_   320         // 5 waves per block
#define ASTRIDE 68          // A-slab row stride bytes (32c*2B + 4B pad -> 2-way banks)
#define TSTR    404         // epilogue transpose stride (f32), 16B-aligned

__device__ __forceinline__ unsigned short f2bf(float f) {
  unsigned u = __builtin_bit_cast(unsigned, f);
  return (unsigned short)((u + 0x7FFFu + ((u >> 16) & 1u)) >> 16);
}

// --- P0: pack Ws into MFMA B-fragment layout -------------------------------
// Wg entry idx = ((s*2+chunk)*4 + ni)*64 + lane ; 8 bf16 per entry:
//   elem j = Ws[s][ o = ni*16 + (lane&15) ][ c = chunk*32 + (lane>>4)*8 + j ]
__global__ void pack_w_kernel(const float* __restrict__ W, s16x8* __restrict__ Wg) {
  int idx = blockIdx.x * 256 + threadIdx.x;
  if (idx >= 12800) return;
  int lane  = idx & 63;
  int ni    = (idx >> 6) & 3;
  int chunk = (idx >> 8) & 1;
  int s     = idx >> 9;
  int o     = (ni << 4) + (lane & 15);
  int cbase = (chunk << 5) + ((lane >> 4) << 3);
  s16x8 h;
#pragma unroll
  for (int j = 0; j < 8; ++j) {
    int c = cbase + j;
    float val;
    if (s == 0) {
      val = 0.f;
      for (int i = 0; i < 24; ++i) val += W[((i * 64 + o) * 64 + c) * 2];
    } else {
      val = W[(((s - 1) * 64 + o) * 64 + c) * 2 + 1];
    }
    h[j] = (short)f2bf(val);
  }
  Wg[idx] = h;
}

// One shift-phase: consume af x BF (per-r interleave: ds_read next frag, 4 MFMA,
// rotate), then reload BF with the s+2 B-fragments (2-phase L2 cover).
// NOTE: macro-local variable is hygienically named (nxs_) — round-4 crash was
// `int sp = 2*sp+2` self-shadowing UB from the call-site loop variable.
#define PHASE(BF, S_)                                                      \
  {                                                                        \
    _Pragma("unroll")                                                      \
    for (int r = 0; r < 5; ++r) {                                          \
      bool w = (u[r] == 24);                                               \
      u[r]  = w ? 0 : u[r] + 1;                                            \
      ao[r] += w ? -(24 * ASTRIDE) : ASTRIDE;                              \
    }                                                                      \
    __builtin_amdgcn_s_setprio(1);                                         \
    _Pragma("unroll")                                                      \
    for (int r = 0; r < 5; ++r) {                                          \
      s16x8 t = *(const s16x8*)(Ash + ao[r]);                              \
      _Pragma("unroll")                                                    \
      for (int ct = 0; ct < 4; ++ct)                                       \
        acc[r][ct] = __builtin_amdgcn_mfma_f32_16x16x32_bf16(              \
            af[r], BF[ct], acc[r][ct], 0, 0, 0);                           \
      af[r] = t;                                                           \
    }                                                                      \
    __builtin_amdgcn_s_setprio(0);                                         \
    int nxs_ = (S_) + 2; nxs_ -= (nxs_ >= 25) ? 25 : 0;                    \
    const s16x8* wq_ = Wg + (((nxs_ << 1) + chunk) << 8);                  \
    _Pragma("unroll")                                                      \
    for (int ni = 0; ni < 4; ++ni) BF[ni] = wq_[(ni << 6) + lane];         \
  }

// --- P1: main tap-GEMM -----------------------------------------------------
// grid (n=64, tb=19), 320 threads = 5 waves. Block owns 400 (t,v)-rows x 64 o.
// Two K-passes (c-chunks of 32); A-slab [400][32c] bf16, stride 68B, in LDS.
// Wave: 5 row-tiles x 4 col-tiles, acc 5x4 f32x4 persists across passes.
__global__ __launch_bounds__(NTHR_, 6) void tap_mm_kernel(
    const float* __restrict__ x, const s16x8* __restrict__ Wg,
    float* __restrict__ out, float* __restrict__ partials) {
  __shared__ __align__(16) char Ash[27200];   // A-slab; epilogue T[16][404] f32
  __shared__ float red2[640];
  int n  = blockIdx.x;
  int tb = blockIdx.y;
  int t0 = tb * 16;
  int validRows = min(16, T_ - t0) * 25;
  int tid = threadIdx.x;
  const float* xn = x + n * 480000 + t0 * 25;

  int wid = tid >> 6, lane = tid & 63;
  int l15 = lane & 15, lk = lane >> 4;
  int u[5], ao[5];                      // ao = srow*ASTRIDE + lk*16
#pragma unroll
  for (int r = 0; r < 5; ++r) {
    int orow = ((wid * 5 + r) << 4) + l15;   // A-side row this lane feeds
    int tL = orow / 25;
    u[r]  = orow - tL * 25;                  // = v; cycles with s, period 25
    ao[r] = orow * ASTRIDE + (lk << 4);
  }
  f32x4 acc[5][4];
#pragma unroll
  for (int r = 0; r < 5; ++r)
#pragma unroll
    for (int ct = 0; ct < 4; ++ct) acc[r][ct] = (f32x4){0.f, 0.f, 0.f, 0.f};

  for (int pass = 0; pass < 2; ++pass) {
    int chunk = pass;
    if (pass) __syncthreads();     // all waves done reading Ash (pass-0 data)
    // ---- stage A half-chunk: 1600 tasks of {8 strided c-loads -> 16B ds_write}
    int cbase = chunk << 5;
#pragma unroll
    for (int it = 0; it < 5; ++it) {
      int id  = tid + it * NTHR_;      // [0,1600) = g*400 + pos
      int pos = id % 400;              // t_local*25 + u (contiguous in x)
      int g   = id / 400;              // c-subgroup (8 c's)
      int c0  = cbase + (g << 3);
      bool vld = pos < validRows;
      s16x8 h;
#pragma unroll
      for (int j = 0; j < 8; ++j) {
        float f = vld ? xn[(c0 + j) * 7500 + pos] : 0.f;
        h[j] = (short)f2bf(f);
      }
      *(s16x8*)(Ash + pos * ASTRIDE + (g << 4)) = h;
    }
    __syncthreads();

    // ---- prologue: A-frags for s=0, B-frags for s=0 and s=1
    s16x8 af[5];
#pragma unroll
    for (int r = 0; r < 5; ++r) af[r] = *(const s16x8*)(Ash + ao[r]);
    s16x8 bfA[4], bfB[4];
    {
      const s16x8* wq0 = Wg + (chunk << 8);
      const s16x8* wq1 = Wg + ((2 + chunk) << 8);
#pragma unroll
      for (int ni = 0; ni < 4; ++ni) bfA[ni] = wq0[(ni << 6) + lane];
#pragma unroll
      for (int ni = 0; ni < 4; ++ni) bfB[ni] = wq1[(ni << 6) + lane];
    }

    // ---- 25 shift-phases (static bfA/bfB alternation; tail phase = bfA)
    for (int sp = 0; sp < 12; ++sp) {
      PHASE(bfA, 2 * sp);
      PHASE(bfB, 2 * sp + 1);
    }
    PHASE(bfA, 24);
    // u/ao cycled back to initial state; ready for next pass
  }

  // ---- per-channel sum/sumsq from registers (valid rows only)
  float s1v[4] = {0.f, 0.f, 0.f, 0.f}, s2v[4] = {0.f, 0.f, 0.f, 0.f};
#pragma unroll
  for (int r = 0; r < 5; ++r) {
#pragma unroll
    for (int qq = 0; qq < 4; ++qq) {
      int orow = ((wid * 5 + r) << 4) + (lk << 2) + qq;  // C/D: row=(l>>4)*4+reg
      if (orow < validRows) {
#pragma unroll
        for (int ct = 0; ct < 4; ++ct) {
          float val = acc[r][ct][qq];
          s1v[ct] += val;
          s2v[ct] += val * val;
        }
      }
    }
  }
#pragma unroll
  for (int ct = 0; ct < 4; ++ct) {
    float a = s1v[ct], b = s2v[ct];
    a += __shfl_xor(a, 16); a += __shfl_xor(a, 32);
    b += __shfl_xor(b, 16); b += __shfl_xor(b, 32);
    if (lane < 16) {
      int base = ((((wid << 2) + ct) << 4) + l15) * 2;
      red2[base]     = a;
      red2[base + 1] = b;
    }
  }

  // ---- epilogue: 4 o-quarters through LDS transpose, coalesced f4 stores
  float* T = (float*)Ash;
  float* outb = out + n * 480000 + tb * 400;   // + o*7500 + row
  for (int qt = 0; qt < 4; ++qt) {
    __syncthreads();   // qt=0: K-loop Ash reads + red2 writes done; else T reads done
    // write acc[.][qt] -> T[o_local][row]
#pragma unroll
    for (int r = 0; r < 5; ++r) {
      int row0 = wid * 80 + r * 16 + (lk << 2);
      *(f32x4*)&T[l15 * TSTR + row0] = acc[r][qt];
    }
    __syncthreads();
    if (qt == 0 && tid < 128) {   // deterministic partial reduction (reads red2)
      int o = tid >> 1, m = tid & 1;
      int ct = o >> 4, ol = o & 15;
      float sres = 0.f;
#pragma unroll
      for (int w = 0; w < 5; ++w) sres += red2[((((w << 2) + ct) << 4) + ol) * 2 + m];
      int bl = blockIdx.y * 64 + blockIdx.x;
      partials[bl * 128 + m * 64 + o] = sres;
    }
    // read T + coalesced global f4 stores: 16 o x 100 f4-rows
#pragma unroll
    for (int i = 0; i < 5; ++i) {
      int idx = tid + i * 320;
      int ol  = idx / 100;
      int r4  = idx - ol * 100;
      if ((r4 << 2) < validRows) {
        float4 v = *(float4*)&T[ol * TSTR + (r4 << 2)];
        *(float4*)&outb[((qt << 4) + ol) * 7500 + (r4 << 2)] = v;
      }
    }
  }
}

// --- P2: reduce per-block partials -> per-channel scale/shift --------------
__global__ void finalize_kernel(const float* __restrict__ part,
                                const float* __restrict__ gamma,
                                const float* __restrict__ beta,
                                float* __restrict__ scsh) {
  __shared__ float sm[512];
  int o = blockIdx.x;            // 64 blocks, one channel each
  int tid = threadIdx.x;         // 256 threads
  float s1 = 0.f, s2 = 0.f;
  for (int b = tid; b < 1216; b += 256) {
    s1 += part[b * 128 + o];
    s2 += part[b * 128 + 64 + o];
  }
  sm[tid] = s1; sm[256 + tid] = s2;
  __syncthreads();
  for (int st = 128; st >= 1; st >>= 1) {
    if (tid < st) { sm[tid] += sm[tid + st]; sm[256 + tid] += sm[256 + tid + st]; }
    __syncthreads();
  }
  if (tid == 0) {
    const float inv = 1.0f / 480000.0f;
    float mean = sm[0] * inv;
    float var  = sm[256] * inv - mean * mean;
    float sc = gamma[o] * rsqrtf(var + 1e-5f);
    float sh = beta[o] - mean * sc;
    scsh[o]      = sc;
    scsh[64 + o] = sh;
  }
}

// --- P3: in-place BN-apply + ReLU, float4 ----------------------------------
__global__ void bn_relu_kernel(float4* __restrict__ out, const float* __restrict__ scsh) {
  int i = blockIdx.x * blockDim.x + threadIdx.x;
  const int total = 7680000;        // 30.72M / 4 ; 7500%4==0 so o uniform per f4
  int stride = gridDim.x * blockDim.x;
  for (; i < total; i += stride) {
    int o = (i / 1875) & 63;
    float sc = scsh[o], sh = scsh[64 + o];
    float4 v = out[i];
    v.x = fmaxf(fmaf(v.x, sc, sh), 0.f);
    v.y = fmaxf(fmaf(v.y, sc, sh), 0.f);
    v.z = fmaxf(fmaf(v.z, sc, sh), 0.f);
    v.w = fmaxf(fmaf(v.w, sc, sh), 0.f);
    out[i] = v;
  }
}

// ---------------------------------------------------------------------------
extern "C" void kernel_launch(void* const* d_in, const int* in_sizes, int n_in,
                              void* d_out, int out_size, void* d_ws, size_t ws_size,
                              hipStream_t stream) {
  const float* x     = (const float*)d_in[0];
  const float* W     = (const float*)d_in[1];
  // d_in[2] = b : cancels under batch-norm, unused.
  const float* gamma = (const float*)d_in[3];
  const float* beta  = (const float*)d_in[4];
  float* out = (float*)d_out;

  char* ws = (char*)d_ws;
  s16x8* Wg       = (s16x8*)ws;                       // 204,800 B
  float* partials = (float*)(ws + 204800);            // 1216*128*4 = 622,592 B
  float* scsh     = (float*)(ws + 204800 + 622592);   // 512 B

  pack_w_kernel<<<dim3(50), dim3(256), 0, stream>>>(W, Wg);
  tap_mm_kernel<<<dim3(64, TB_), dim3(NTHR_), 0, stream>>>(x, Wg, out, partials);
  finalize_kernel<<<dim3(64), dim3(256), 0, stream>>>(partials, gamma, beta, scsh);
  bn_relu_kernel<<<dim3(2048), dim3(256), 0, stream>>>((float4*)out, scsh);
}

// Round 6
// 328.825 us; speedup vs baseline: 6.8214x; 6.8214x over previous
//
#include <hip/hip_runtime.h>

// ---------------------------------------------------------------------------
// unit_gcn: out[n,o,t,v] = BN+ReLU of  sum_{s=0..24} Ws[s] @_c x[n,:,t,(v+s)%25]
//   Ws[0] = sum_i W[i,:,:,0];  Ws[s] = W[s-1,:,:,1]  (s>=1); bias cancels in BN.
// N=64, C=64, T=300, V=25, O=64.  x fp32 -> bf16 MFMA (16x16x32), fp32 accum.
// v3: zero in-loop global traffic. A (27.2KB) + B double-buffered groups
// (2x20KB) all in LDS; B reg-staged with issue-early/write-late (T14).
// ---------------------------------------------------------------------------

typedef short  s16x8 __attribute__((ext_vector_type(8)));
typedef float  f32x4 __attribute__((ext_vector_type(4)));

#define T_      300
#define TB_     19          // ceil(300/16) t-blocks
#define NTHR_   320         // 5 waves per block
#define ASTRIDE 68          // A-slab row stride bytes (32c*2B + 4B pad)
#define TSTR    404         // epilogue transpose stride (f32)

__device__ __forceinline__ unsigned short f2bf(float f) {
  unsigned u = __builtin_bit_cast(unsigned, f);
  return (unsigned short)((u + 0x7FFFu + ((u >> 16) & 1u)) >> 16);
}

// --- P0: pack Ws into MFMA B-fragment layout, CHUNK-MAJOR ------------------
// Wg entry idx = ((chunk*25 + s)*4 + ni)*64 + lane ; 8 bf16 per entry:
//   elem j = Ws[s][ o = ni*16 + (lane&15) ][ c = chunk*32 + (lane>>4)*8 + j ]
__global__ void pack_w_kernel(const float* __restrict__ W, s16x8* __restrict__ Wg) {
  int idx = blockIdx.x * 256 + threadIdx.x;
  if (idx >= 12800) return;
  int lane  = idx & 63;
  int rest  = idx >> 6;
  int ni    = rest & 3;
  int sc    = rest >> 2;       // chunk*25 + s
  int s     = sc % 25;
  int chunk = sc / 25;
  int o     = (ni << 4) + (lane & 15);
  int cbase = (chunk << 5) + ((lane >> 4) << 3);
  s16x8 h;
#pragma unroll
  for (int j = 0; j < 8; ++j) {
    int c = cbase + j;
    float val;
    if (s == 0) {
      val = 0.f;
      for (int i = 0; i < 24; ++i) val += W[((i * 64 + o) * 64 + c) * 2];
    } else {
      val = W[(((s - 1) * 64 + o) * 64 + c) * 2 + 1];
    }
    h[j] = (short)f2bf(val);
  }
  Wg[idx] = h;
}

// --- P1: main tap-GEMM -----------------------------------------------------
// grid (n=64, tb=19), 320 threads = 5 waves. Block owns 400 (t,v)-rows x 64 o.
// chunk pass (c-half): stage A [400][32c] LDS; s-groups of 5 with B in LDS
// double buffer (reg-staged, issued 2 groups early). No global ops in phases.
__global__ __launch_bounds__(NTHR_) void tap_mm_kernel(
    const float* __restrict__ x, const s16x8* __restrict__ Wg,
    float* __restrict__ out, float* __restrict__ partials) {
  __shared__ __align__(16) char Ash[27200];      // A-slab; epilogue T[16][404] f32
  __shared__ __align__(16) char Bsh[2][20480];   // B group double buffer
  __shared__ float red2[640];
  int n  = blockIdx.x;
  int tb = blockIdx.y;
  int t0 = tb * 16;
  int validRows = min(16, T_ - t0) * 25;
  int tid = threadIdx.x;
  const float* xn = x + n * 480000 + t0 * 25;

  int wid = tid >> 6, lane = tid & 63;
  int l15 = lane & 15, lk = lane >> 4;
  int u[5], ao[5];                      // ao = srow*ASTRIDE + lk*16
#pragma unroll
  for (int r = 0; r < 5; ++r) {
    int orow = ((wid * 5 + r) << 4) + l15;   // A-side row this lane feeds
    int tL = orow / 25;
    u[r]  = orow - tL * 25;                  // = v; cycles with s, period 25
    ao[r] = orow * ASTRIDE + (lk << 4);
  }
  f32x4 acc[5][4];
#pragma unroll
  for (int r = 0; r < 5; ++r)
#pragma unroll
    for (int ct = 0; ct < 4; ++ct) acc[r][ct] = (f32x4){0.f, 0.f, 0.f, 0.f};

  // B reg-staging: thread covers flat s16x8 entries {it*320+tid} of a 1280-entry
  // (20480B) group. Issue chunk0/group0 now; arrives during A staging.
  s16x8 Breg[4];
#pragma unroll
  for (int it = 0; it < 4; ++it) Breg[it] = Wg[it * 320 + tid];

  for (int chunk = 0; chunk < 2; ++chunk) {
    if (chunk) __syncthreads();    // all waves done with pass-0 A & Bsh[0]
    // ---- stage A half-chunk: 1600 tasks of {8 strided c-loads -> 16B ds_write}
    int cbase = chunk << 5;
#pragma unroll
    for (int it = 0; it < 5; ++it) {
      int id  = tid + it * NTHR_;      // [0,1600) = g*400 + pos
      int pos = id % 400;              // t_local*25 + u (contiguous in x)
      int g   = id / 400;              // c-subgroup (8 c's)
      int c0  = cbase + (g << 3);
      bool vld = pos < validRows;
      s16x8 h;
#pragma unroll
      for (int j = 0; j < 8; ++j) {
        float f = vld ? xn[(c0 + j) * 7500 + pos] : 0.f;
        h[j] = (short)f2bf(f);
      }
      *(s16x8*)(Ash + pos * ASTRIDE + (g << 4)) = h;
    }
    // ---- B preamble: write group0 regs -> Bsh[0]; issue group1 loads
#pragma unroll
    for (int it = 0; it < 4; ++it)
      *(s16x8*)(Bsh[0] + (it * 320 + tid) * 16) = Breg[it];
    {
      const s16x8* src = Wg + (chunk * 25 + 5) * 256;
#pragma unroll
      for (int it = 0; it < 4; ++it) Breg[it] = src[it * 320 + tid];
    }
    __syncthreads();                 // A-slab + Bsh[0] ready

    // ---- A-frag preload for shift 0 of this chunk
    s16x8 af[5];
#pragma unroll
    for (int r = 0; r < 5; ++r) af[r] = *(const s16x8*)(Ash + ao[r]);

    // ---- 5 s-groups x 5 shifts
    for (int g = 0; g < 5; ++g) {
      const char* Bb = Bsh[g & 1];
#pragma unroll
      for (int sl = 0; sl < 5; ++sl) {
        // current-phase B frags from LDS (base + imm offsets)
        s16x8 bf0 = *(const s16x8*)(Bb + ((sl * 4 + 0) * 64 + lane) * 16);
        s16x8 bf1 = *(const s16x8*)(Bb + ((sl * 4 + 1) * 64 + lane) * 16);
        s16x8 bf2 = *(const s16x8*)(Bb + ((sl * 4 + 2) * 64 + lane) * 16);
        s16x8 bf3 = *(const s16x8*)(Bb + ((sl * 4 + 3) * 64 + lane) * 16);
        // advance shift (prefetch target = next shift's A rows)
#pragma unroll
        for (int r = 0; r < 5; ++r) {
          bool w = (u[r] == 24);
          u[r]  = w ? 0 : u[r] + 1;
          ao[r] += w ? -(24 * ASTRIDE) : ASTRIDE;
        }
        __builtin_amdgcn_s_setprio(1);
#pragma unroll
        for (int r = 0; r < 5; ++r) {
          s16x8 t = *(const s16x8*)(Ash + ao[r]);   // next-shift A frag
          acc[r][0] = __builtin_amdgcn_mfma_f32_16x16x32_bf16(af[r], bf0, acc[r][0], 0, 0, 0);
          acc[r][1] = __builtin_amdgcn_mfma_f32_16x16x32_bf16(af[r], bf1, acc[r][1], 0, 0, 0);
          acc[r][2] = __builtin_amdgcn_mfma_f32_16x16x32_bf16(af[r], bf2, acc[r][2], 0, 0, 0);
          acc[r][3] = __builtin_amdgcn_mfma_f32_16x16x32_bf16(af[r], bf3, acc[r][3], 0, 0, 0);
          af[r] = t;
        }
        __builtin_amdgcn_s_setprio(0);
      }
      // group end: publish next group's B; issue loads 2 groups ahead
      if (g < 4) {
        char* Bw = Bsh[(g + 1) & 1];
#pragma unroll
        for (int it = 0; it < 4; ++it)
          *(s16x8*)(Bw + (it * 320 + tid) * 16) = Breg[it];
        int nsc;                        // group whose loads we issue now
        if (g < 3)       nsc = chunk * 25 + (g + 2) * 5;   // within chunk
        else if (!chunk) nsc = 25;                         // chunk1 group0
        else             nsc = 0;                          // dummy (harmless)
        const s16x8* src = Wg + nsc * 256;
#pragma unroll
        for (int it = 0; it < 4; ++it) Breg[it] = src[it * 320 + tid];
      }
      __syncthreads();
    }
  }

  // ---- per-channel sum/sumsq from registers (valid rows only)
  float s1v[4] = {0.f, 0.f, 0.f, 0.f}, s2v[4] = {0.f, 0.f, 0.f, 0.f};
#pragma unroll
  for (int r = 0; r < 5; ++r) {
#pragma unroll
    for (int qq = 0; qq < 4; ++qq) {
      int orow = ((wid * 5 + r) << 4) + (lk << 2) + qq;  // C/D: row=(l>>4)*4+reg
      if (orow < validRows) {
#pragma unroll
        for (int ct = 0; ct < 4; ++ct) {
          float val = acc[r][ct][qq];
          s1v[ct] += val;
          s2v[ct] += val * val;
        }
      }
    }
  }
#pragma unroll
  for (int ct = 0; ct < 4; ++ct) {
    float a = s1v[ct], b = s2v[ct];
    a += __shfl_xor(a, 16); a += __shfl_xor(a, 32);
    b += __shfl_xor(b, 16); b += __shfl_xor(b, 32);
    if (lane < 16) {
      int base = ((((wid << 2) + ct) << 4) + l15) * 2;
      red2[base]     = a;
      red2[base + 1] = b;
    }
  }

  // ---- epilogue: 4 o-quarters through LDS transpose, coalesced f4 stores
  float* T = (float*)Ash;
  float* outb = out + n * 480000 + tb * 400;   // + o*7500 + row
  for (int qt = 0; qt < 4; ++qt) {
    __syncthreads();   // qt=0: K-loop Ash/Bsh reads + red2 writes done; else T reads
    // write acc[.][qt] -> T[o_local][row]
#pragma unroll
    for (int r = 0; r < 5; ++r) {
      int row0 = wid * 80 + r * 16 + (lk << 2);
      *(f32x4*)&T[l15 * TSTR + row0] = acc[r][qt];
    }
    __syncthreads();
    if (qt == 0 && tid < 128) {   // deterministic partial reduction (reads red2)
      int o = tid >> 1, m = tid & 1;
      int ct = o >> 4, ol = o & 15;
      float sres = 0.f;
#pragma unroll
      for (int w = 0; w < 5; ++w) sres += red2[((((w << 2) + ct) << 4) + ol) * 2 + m];
      int bl = blockIdx.y * 64 + blockIdx.x;
      partials[bl * 128 + m * 64 + o] = sres;
    }
    // read T + coalesced global f4 stores: 16 o x 100 f4-rows
#pragma unroll
    for (int i = 0; i < 5; ++i) {
      int idx = tid + i * 320;
      int ol  = idx / 100;
      int r4  = idx - ol * 100;
      if ((r4 << 2) < validRows) {
        float4 v = *(float4*)&T[ol * TSTR + (r4 << 2)];
        *(float4*)&outb[((qt << 4) + ol) * 7500 + (r4 << 2)] = v;
      }
    }
  }
}

// --- P2: reduce per-block partials -> per-channel scale/shift --------------
__global__ void finalize_kernel(const float* __restrict__ part,
                                const float* __restrict__ gamma,
                                const float* __restrict__ beta,
                                float* __restrict__ scsh) {
  __shared__ float sm[512];
  int o = blockIdx.x;            // 64 blocks, one channel each
  int tid = threadIdx.x;         // 256 threads
  float s1 = 0.f, s2 = 0.f;
  for (int b = tid; b < 1216; b += 256) {
    s1 += part[b * 128 + o];
    s2 += part[b * 128 + 64 + o];
  }
  sm[tid] = s1; sm[256 + tid] = s2;
  __syncthreads();
  for (int st = 128; st >= 1; st >>= 1) {
    if (tid < st) { sm[tid] += sm[tid + st]; sm[256 + tid] += sm[256 + tid + st]; }
    __syncthreads();
  }
  if (tid == 0) {
    const float inv = 1.0f / 480000.0f;
    float mean = sm[0] * inv;
    float var  = sm[256] * inv - mean * mean;
    float sc = gamma[o] * rsqrtf(var + 1e-5f);
    float sh = beta[o] - mean * sc;
    scsh[o]      = sc;
    scsh[64 + o] = sh;
  }
}

// --- P3: in-place BN-apply + ReLU, float4 ----------------------------------
__global__ void bn_relu_kernel(float4* __restrict__ out, const float* __restrict__ scsh) {
  int i = blockIdx.x * blockDim.x + threadIdx.x;
  const int total = 7680000;        // 30.72M / 4 ; 7500%4==0 so o uniform per f4
  int stride = gridDim.x * blockDim.x;
  for (; i < total; i += stride) {
    int o = (i / 1875) & 63;
    float sc = scsh[o], sh = scsh[64 + o];
    float4 v = out[i];
    v.x = fmaxf(fmaf(v.x, sc, sh), 0.f);
    v.y = fmaxf(fmaf(v.y, sc, sh), 0.f);
    v.z = fmaxf(fmaf(v.z, sc, sh), 0.f);
    v.w = fmaxf(fmaf(v.w, sc, sh), 0.f);
    out[i] = v;
  }
}

// ---------------------------------------------------------------------------
extern "C" void kernel_launch(void* const* d_in, const int* in_sizes, int n_in,
                              void* d_out, int out_size, void* d_ws, size_t ws_size,
                              hipStream_t stream) {
  const float* x     = (const float*)d_in[0];
  const float* W     = (const float*)d_in[1];
  // d_in[2] = b : cancels under batch-norm, unused.
  const float* gamma = (const float*)d_in[3];
  const float* beta  = (const float*)d_in[4];
  float* out = (float*)d_out;

  char* ws = (char*)d_ws;
  s16x8* Wg       = (s16x8*)ws;                       // 204,800 B
  float* partials = (float*)(ws + 204800);            // 1216*128*4 = 622,592 B
  float* scsh     = (float*)(ws + 204800 + 622592);   // 512 B

  pack_w_kernel<<<dim3(50), dim3(256), 0, stream>>>(W, Wg);
  tap_mm_kernel<<<dim3(64, TB_), dim3(NTHR_), 0, stream>>>(x, Wg, out, partials);
  finalize_kernel<<<dim3(64), dim3(256), 0, stream>>>(partials, gamma, beta, scsh);
  bn_relu_kernel<<<dim3(2048), dim3(256), 0, stream>>>((float4*)out, scsh);
}

// Round 7
// 328.499 us; speedup vs baseline: 6.8281x; 1.0010x over previous
//
#include <hip/hip_runtime.h>

// ---------------------------------------------------------------------------
// unit_gcn: out[n,o,t,v] = BN+ReLU of  sum_{s=0..24} Ws[s] @_c x[n,:,t,(v+s)%25]
//   Ws[0] = sum_i W[i,:,:,0];  Ws[s] = W[s-1,:,:,1]  (s>=1); bias cancels in BN.
// N=64, C=64, T=300, V=25, O=64.  x fp32 -> bf16 MFMA (16x16x32), fp32 accum.
// v4: 8 balanced waves (4 row x 2 col), acc 32 regs, 16 waves/CU; slab rows
// flat (not t-aligned), stride 80B (16B-aligned b128); B global->reg 2-deep;
// no barriers in the 25-phase shift loop; two 32-c chunk passes.
// ---------------------------------------------------------------------------

typedef short  s16x8 __attribute__((ext_vector_type(8)));
typedef float  f32x4 __attribute__((ext_vector_type(4)));

#define NTHR_   512
#define RPB_    256         // output rows per block (flat (t,v) rows)
#define NBR_    30          // ceil(7500/256) row-blocks per n
#define SLAB_   300         // max slab rows (t-span*25 <= 300)
#define ASTR    80          // slab row stride bytes (32c*2B + 16 pad; 16B-aligned)
#define TS_     260         // epilogue transpose stride (f32)

__device__ __forceinline__ unsigned short f2bf(float f) {
  unsigned u = __builtin_bit_cast(unsigned, f);
  return (unsigned short)((u + 0x7FFFu + ((u >> 16) & 1u)) >> 16);
}

// --- P0: pack Ws into MFMA B-fragment layout, CHUNK-MAJOR ------------------
// Wg entry idx = ((chunk*25 + s)*4 + ni)*64 + lane ; 8 bf16 per entry:
//   elem j = Ws[s][ o = ni*16 + (lane&15) ][ c = chunk*32 + (lane>>4)*8 + j ]
__global__ void pack_w_kernel(const float* __restrict__ W, s16x8* __restrict__ Wg) {
  int idx = blockIdx.x * 256 + threadIdx.x;
  if (idx >= 12800) return;
  int lane  = idx & 63;
  int rest  = idx >> 6;
  int ni    = rest & 3;
  int sc    = rest >> 2;       // chunk*25 + s
  int s     = sc % 25;
  int chunk = sc / 25;
  int o     = (ni << 4) + (lane & 15);
  int cbase = (chunk << 5) + ((lane >> 4) << 3);
  s16x8 h;
#pragma unroll
  for (int j = 0; j < 8; ++j) {
    int c = cbase + j;
    float val;
    if (s == 0) {
      val = 0.f;
      for (int i = 0; i < 24; ++i) val += W[((i * 64 + o) * 64 + c) * 2];
    } else {
      val = W[(((s - 1) * 64 + o) * 64 + c) * 2 + 1];
    }
    h[j] = (short)f2bf(val);
  }
  Wg[idx] = h;
}

// One shift-phase: advance shift addrs, read next-shift A-frags into AFN while
// doing 8 MFMAs on AFC x (B0,B1); then prefetch B for s+2 into the just-
// consumed B regs (2-phase L2 cover, WAR-ordered after the MFMAs).
#define PH(AFC, AFN, B0, B1, S_)                                           \
  {                                                                        \
    _Pragma("unroll")                                                      \
    for (int rt = 0; rt < 4; ++rt) {                                       \
      bool w = (u[rt] == 24);                                              \
      u[rt]  = w ? 0 : u[rt] + 1;                                          \
      ao[rt] += w ? -(24 * ASTR) : ASTR;                                   \
    }                                                                      \
    __builtin_amdgcn_s_setprio(1);                                         \
    _Pragma("unroll")                                                      \
    for (int rt = 0; rt < 4; ++rt) {                                       \
      AFN[rt] = *(const s16x8*)(Ash + ao[rt]);                             \
      acc[rt][0] = __builtin_amdgcn_mfma_f32_16x16x32_bf16(                \
          AFC[rt], B0, acc[rt][0], 0, 0, 0);                               \
      acc[rt][1] = __builtin_amdgcn_mfma_f32_16x16x32_bf16(                \
          AFC[rt], B1, acc[rt][1], 0, 0, 0);                               \
    }                                                                      \
    __builtin_amdgcn_s_setprio(0);                                         \
    int ns_ = (S_) + 2; ns_ -= (ns_ >= 25) ? 25 : 0;                       \
    B0 = WgC[(ns_ << 8) + (ni0 << 6) + lane];                              \
    B1 = WgC[(ns_ << 8) + (ni1 << 6) + lane];                              \
  }

// --- P1: main tap-GEMM -----------------------------------------------------
// grid (rowblk=30, n=64), 512 thr = 8 waves (wr=wid>>1 row-group, wc=wid&1
// o-half). Block owns 256 flat rows x 64 o. Slab: covering t-span x 32c.
__global__ __launch_bounds__(NTHR_, 4) void tap_mm_kernel(
    const float* __restrict__ x, const s16x8* __restrict__ Wg,
    float* __restrict__ out, float* __restrict__ partials) {
  __shared__ __align__(16) char Ash[SLAB_ * ASTR];   // 24000B; epilogue T[16][260] f32
  __shared__ float red2[512];
  int br = blockIdx.x, n = blockIdx.y;
  int r0 = br * RPB_;
  int validR = 7500 - r0;              // rows this block really owns (>=256 except last)
  int t0g = r0 / 25;
  int tlast = (r0 + min(RPB_, validR) - 1) / 25;
  int slabRows = (tlast - t0g + 1) * 25;   // <= 300
  const float* xn = x + n * 480000;
  int xbase = t0g * 25;

  int tid = threadIdx.x;
  int wid = tid >> 6, lane = tid & 63;
  int wr = wid >> 1, wc = wid & 1;
  int l15 = lane & 15, lk = lane >> 4;
  int ni0 = wc << 1, ni1 = ni0 + 1;

  int u[4], ao[4];                     // ao = slabRow*ASTR + lk*16
#pragma unroll
  for (int rt = 0; rt < 4; ++rt) {
    int gr = r0 + ((wr * 4 + rt) << 4) + l15;   // row this lane feeds (A-side)
    int tL = gr / 25;
    u[rt]  = gr - tL * 25;
    ao[rt] = ((tL - t0g) * 25 + u[rt]) * ASTR + (lk << 4);
  }
  f32x4 acc[4][2];
#pragma unroll
  for (int rt = 0; rt < 4; ++rt) {
    acc[rt][0] = (f32x4){0.f, 0.f, 0.f, 0.f};
    acc[rt][1] = (f32x4){0.f, 0.f, 0.f, 0.f};
  }

  for (int chunk = 0; chunk < 2; ++chunk) {
    if (chunk) __syncthreads();        // all waves done reading chunk-0 slab
    int cbase = chunk << 5;
    // ---- stage slab: up to 1200 tasks {8 strided c-loads -> 16B ds_write}
#pragma unroll
    for (int it = 0; it < 3; ++it) {
      int id = tid + it * NTHR_;       // [0,1536)
      if (id < 1200) {
        int g = id / 300, pos = id - g * 300;
        bool vld = pos < slabRows;
        s16x8 h;
#pragma unroll
        for (int j = 0; j < 8; ++j) {
          float f = vld ? xn[(cbase + (g << 3) + j) * 7500 + xbase + pos] : 0.f;
          h[j] = (short)f2bf(f);
        }
        *(s16x8*)(Ash + pos * ASTR + (g << 4)) = h;   // zeros beyond slabRows
      }
    }
    __syncthreads();

    // ---- prologue: B for s=0,1 (global, L2-hot); A-frags for s=0
    const s16x8* WgC = Wg + chunk * 25 * 256;
    s16x8 bfA0 = WgC[(ni0 << 6) + lane];
    s16x8 bfA1 = WgC[(ni1 << 6) + lane];
    s16x8 bfB0 = WgC[256 + (ni0 << 6) + lane];
    s16x8 bfB1 = WgC[256 + (ni1 << 6) + lane];
    s16x8 afA[4], afB[4];
#pragma unroll
    for (int rt = 0; rt < 4; ++rt) afA[rt] = *(const s16x8*)(Ash + ao[rt]);

    // ---- 25 shift-phases, no barriers
    for (int sp = 0; sp < 12; ++sp) {
      PH(afA, afB, bfA0, bfA1, 2 * sp);
      PH(afB, afA, bfB0, bfB1, 2 * sp + 1);
    }
    PH(afA, afB, bfA0, bfA1, 24);
    // u/ao cycled back to initial state for next chunk
  }

  // ---- per-channel sum/sumsq from registers (valid rows only)
  float s1v[2] = {0.f, 0.f}, s2v[2] = {0.f, 0.f};
#pragma unroll
  for (int rt = 0; rt < 4; ++rt) {
#pragma unroll
    for (int qq = 0; qq < 4; ++qq) {
      int rloc = ((wr * 4 + rt) << 4) + (lk << 2) + qq;   // C/D row
      if (rloc < validR) {
#pragma unroll
        for (int ct = 0; ct < 2; ++ct) {
          float val = acc[rt][ct][qq];
          s1v[ct] += val;
          s2v[ct] += val * val;
        }
      }
    }
  }
#pragma unroll
  for (int ct = 0; ct < 2; ++ct) {
    float a = s1v[ct], b = s2v[ct];
    a += __shfl_xor(a, 16); a += __shfl_xor(a, 32);
    b += __shfl_xor(b, 16); b += __shfl_xor(b, 32);
    if (lane < 16) {
      int base = (((wid << 1) + ct) << 4) + l15;
      red2[base * 2]     = a;
      red2[base * 2 + 1] = b;
    }
  }

  // ---- epilogue: 4 o-quarters via LDS transpose, coalesced f4 stores
  float* T = (float*)Ash;
  float* outb = out + n * 480000 + r0;     // + o*7500 + row
  for (int qt = 0; qt < 4; ++qt) {
    __syncthreads();   // qt=0: slab reads + red2 writes done; else: T reads done
    if ((qt >> 1) == wc) {
      int ct = qt & 1;
#pragma unroll
      for (int rt = 0; rt < 4; ++rt) {
        int row0 = ((wr * 4 + rt) << 4) + (lk << 2);
        *(f32x4*)&T[l15 * TS_ + row0] = acc[rt][ct];
      }
    }
    __syncthreads();
    if (qt == 0 && tid < 128) {   // deterministic partial reduction
      int o = tid >> 1, m = tid & 1;
      int wc2 = o >> 5, ct2 = (o >> 4) & 1, ol = o & 15;
      float sres = 0.f;
#pragma unroll
      for (int w2 = 0; w2 < 4; ++w2)
        sres += red2[(((((w2 << 1) + wc2) << 1) + ct2) * 16 + ol) * 2 + m];
      int bl = blockIdx.y * NBR_ + blockIdx.x;
      partials[bl * 128 + m * 64 + o] = sres;
    }
    // read T + coalesced global f4 stores: 16 o x 64 f4-rows
#pragma unroll
    for (int it = 0; it < 2; ++it) {
      int idx = tid + it * NTHR_;
      int ol = idx >> 6, r4 = idx & 63;
      if ((r4 << 2) < validR) {
        float4 v = *(float4*)&T[ol * TS_ + (r4 << 2)];
        *(float4*)&outb[((qt << 4) + ol) * 7500 + (r4 << 2)] = v;
      }
    }
  }
}

// --- P2: reduce per-block partials -> per-channel scale/shift --------------
__global__ void finalize_kernel(const float* __restrict__ part,
                                const float* __restrict__ gamma,
                                const float* __restrict__ beta,
                                float* __restrict__ scsh) {
  __shared__ float sm[512];
  int o = blockIdx.x;            // 64 blocks, one channel each
  int tid = threadIdx.x;         // 256 threads
  float s1 = 0.f, s2 = 0.f;
  for (int b = tid; b < 1920; b += 256) {
    s1 += part[b * 128 + o];
    s2 += part[b * 128 + 64 + o];
  }
  sm[tid] = s1; sm[256 + tid] = s2;
  __syncthreads();
  for (int st = 128; st >= 1; st >>= 1) {
    if (tid < st) { sm[tid] += sm[tid + st]; sm[256 + tid] += sm[256 + tid + st]; }
    __syncthreads();
  }
  if (tid == 0) {
    const float inv = 1.0f / 480000.0f;
    float mean = sm[0] * inv;
    float var  = sm[256] * inv - mean * mean;
    float sc = gamma[o] * rsqrtf(var + 1e-5f);
    float sh = beta[o] - mean * sc;
    scsh[o]      = sc;
    scsh[64 + o] = sh;
  }
}

// --- P3: in-place BN-apply + ReLU, float4 ----------------------------------
__global__ void bn_relu_kernel(float4* __restrict__ out, const float* __restrict__ scsh) {
  int i = blockIdx.x * blockDim.x + threadIdx.x;
  const int total = 7680000;        // 30.72M / 4 ; 7500%4==0 so o uniform per f4
  int stride = gridDim.x * blockDim.x;
  for (; i < total; i += stride) {
    int o = (i / 1875) & 63;
    float sc = scsh[o], sh = scsh[64 + o];
    float4 v = out[i];
    v.x = fmaxf(fmaf(v.x, sc, sh), 0.f);
    v.y = fmaxf(fmaf(v.y, sc, sh), 0.f);
    v.z = fmaxf(fmaf(v.z, sc, sh), 0.f);
    v.w = fmaxf(fmaf(v.w, sc, sh), 0.f);
    out[i] = v;
  }
}

// ---------------------------------------------------------------------------
extern "C" void kernel_launch(void* const* d_in, const int* in_sizes, int n_in,
                              void* d_out, int out_size, void* d_ws, size_t ws_size,
                              hipStream_t stream) {
  const float* x     = (const float*)d_in[0];
  const float* W     = (const float*)d_in[1];
  // d_in[2] = b : cancels under batch-norm, unused.
  const float* gamma = (const float*)d_in[3];
  const float* beta  = (const float*)d_in[4];
  float* out = (float*)d_out;

  char* ws = (char*)d_ws;
  s16x8* Wg       = (s16x8*)ws;                       // 204,800 B
  float* partials = (float*)(ws + 204800);            // 1920*128*4 = 983,040 B
  float* scsh     = (float*)(ws + 204800 + 983040);   // 512 B

  pack_w_kernel<<<dim3(50), dim3(256), 0, stream>>>(W, Wg);
  tap_mm_kernel<<<dim3(NBR_, 64), dim3(NTHR_), 0, stream>>>(x, Wg, out, partials);
  finalize_kernel<<<dim3(64), dim3(256), 0, stream>>>(partials, gamma, beta, scsh);
  bn_relu_kernel<<<dim3(2048), dim3(256), 0, stream>>>((float4*)out, scsh);
}

// Round 8
// 212.574 us; speedup vs baseline: 10.5518x; 1.5453x over previous
//
#include <hip/hip_runtime.h>

// ---------------------------------------------------------------------------
// unit_gcn: out[n,o,t,v] = BN+ReLU of  sum_{s=0..24} Ws[s] @_c x[n,:,t,(v+s)%25]
//   Ws[0] = sum_i W[i,:,:,0];  Ws[s] = W[s-1,:,:,1]  (s>=1); bias cancels in BN.
// N=64, C=64, T=300, V=25, O=64.  x fp32 -> bf16 MFMA (16x16x32), fp32 accum.
// v5 (R8): one K=64 staging pass; phase = full shift s (40 MFMA between stall
// events, 25 phases); B single-buffer 8 frags reloaded after last use (~1-phase
// cover); serial A rotate register; no min-wave launch bound.
// ---------------------------------------------------------------------------

typedef short  s16x8 __attribute__((ext_vector_type(8)));
typedef float  f32x4 __attribute__((ext_vector_type(4)));

#define T_      300
#define TB_     19          // ceil(300/16) t-blocks
#define NTHR_   320         // 5 waves per block
#define ASTRIDE 136         // A-slab row stride bytes (64c*2B + 8 pad; 16B-aligned)
#define TSTR    404         // epilogue transpose stride (f32)

__device__ __forceinline__ unsigned short f2bf(float f) {
  unsigned u = __builtin_bit_cast(unsigned, f);
  return (unsigned short)((u + 0x7FFFu + ((u >> 16) & 1u)) >> 16);
}

// --- P0: pack Ws into MFMA B-fragment layout (s-major: q = s*2 + chunk) ----
// Wg entry idx = ((s*2+chunk)*4 + ni)*64 + lane ; 8 bf16 per entry:
//   elem j = Ws[s][ o = ni*16 + (lane&15) ][ c = chunk*32 + (lane>>4)*8 + j ]
__global__ void pack_w_kernel(const float* __restrict__ W, s16x8* __restrict__ Wg) {
  int idx = blockIdx.x * 256 + threadIdx.x;
  if (idx >= 12800) return;
  int lane  = idx & 63;
  int ni    = (idx >> 6) & 3;
  int chunk = (idx >> 8) & 1;
  int s     = idx >> 9;
  int o     = (ni << 4) + (lane & 15);
  int cbase = (chunk << 5) + ((lane >> 4) << 3);
  s16x8 h;
#pragma unroll
  for (int j = 0; j < 8; ++j) {
    int c = cbase + j;
    float val;
    if (s == 0) {
      val = 0.f;
      for (int i = 0; i < 24; ++i) val += W[((i * 64 + o) * 64 + c) * 2];
    } else {
      val = W[(((s - 1) * 64 + o) * 64 + c) * 2 + 1];
    }
    h[j] = (short)f2bf(val);
  }
  Wg[idx] = h;
}

// --- P1: main tap-GEMM -----------------------------------------------------
// grid (n=64, tb=19), 320 thr = 5 waves. Block: 400 (t,v)-rows x 64 o.
// A-slab [400][64c] bf16 stride 136B in LDS (staged once). Wave: 5 row-tiles
// x 4 col-tiles, acc 5x4 f32x4. 25 phases; per phase 10 substeps of
// {1 ds_read_b128 (next A-frag), 4 MFMA}; B frags reloaded after last use.
__global__ __launch_bounds__(NTHR_) void tap_mm_kernel(
    const float* __restrict__ x, const s16x8* __restrict__ Wg,
    float* __restrict__ out, float* __restrict__ partials) {
  __shared__ __align__(16) char Ash[54400];   // A-slab; epilogue T[16][404] f32
  __shared__ float red2[640];
  int n  = blockIdx.x;
  int tb = blockIdx.y;
  int t0 = tb * 16;
  int validRows = min(16, T_ - t0) * 25;
  int tid = threadIdx.x;
  const float* xn = x + n * 480000 + t0 * 25;

  // ---- stage A (once, K=64): 3200 tasks {8 strided c-loads -> 16B ds_write}
#pragma unroll 5
  for (int it = 0; it < 10; ++it) {
    int id  = tid + it * NTHR_;        // g*400 + pos
    int pos = id % 400;                // t_local*25 + u (contiguous in x)
    int g   = id / 400;                // c-subgroup (8 c's)
    bool vld = pos < validRows;
    s16x8 h;
#pragma unroll
    for (int j = 0; j < 8; ++j) {
      float f = vld ? xn[((g << 3) + j) * 7500 + pos] : 0.f;
      h[j] = (short)f2bf(f);
    }
    *(s16x8*)(Ash + pos * ASTRIDE + (g << 4)) = h;
  }

  int wid = tid >> 6, lane = tid & 63;
  int l15 = lane & 15, lk = lane >> 4;
  int u[5], ao[5];                      // ao = srow*ASTRIDE + lk*16 (chunk0)
#pragma unroll
  for (int r = 0; r < 5; ++r) {
    int orow = ((wid * 5 + r) << 4) + l15;   // A-side row this lane feeds
    int tL = orow / 25;
    u[r]  = orow - tL * 25;                  // = v; cycles with s, period 25
    ao[r] = orow * ASTRIDE + (lk << 4);
  }
  f32x4 acc[5][4];
#pragma unroll
  for (int r = 0; r < 5; ++r)
#pragma unroll
    for (int ct = 0; ct < 4; ++ct) acc[r][ct] = (f32x4){0.f, 0.f, 0.f, 0.f};

  // B frags for s=0, both chunks (global->reg, L2-hot, reused 24x more)
  s16x8 bf0[4], bf1[4];
#pragma unroll
  for (int ni = 0; ni < 4; ++ni) bf0[ni] = Wg[(ni << 6) + lane];         // q=0
#pragma unroll
  for (int ni = 0; ni < 4; ++ni) bf1[ni] = Wg[256 + (ni << 6) + lane];   // q=1

  __syncthreads();

  // A rotate register preload: frag(s=0, chunk0, r0)
  s16x8 afc = *(const s16x8*)(Ash + ao[0]);

  for (int s = 0; s < 25; ++s) {
    int snx = (s == 24) ? 0 : s + 1;          // prefetch target (dummy on last)
    const s16x8* wq0 = Wg + ((snx << 1) << 8);
    const s16x8* wq1 = wq0 + 256;
    // ---- chunk0 substeps: consume frag(s,c0,r), prefetch next substep
    __builtin_amdgcn_s_setprio(1);
#pragma unroll
    for (int r = 0; r < 5; ++r) {
      s16x8 nx = *(const s16x8*)(Ash + ((r < 4) ? ao[r + 1] : ao[0] + 64));
      acc[r][0] = __builtin_amdgcn_mfma_f32_16x16x32_bf16(afc, bf0[0], acc[r][0], 0, 0, 0);
      acc[r][1] = __builtin_amdgcn_mfma_f32_16x16x32_bf16(afc, bf0[1], acc[r][1], 0, 0, 0);
      acc[r][2] = __builtin_amdgcn_mfma_f32_16x16x32_bf16(afc, bf0[2], acc[r][2], 0, 0, 0);
      acc[r][3] = __builtin_amdgcn_mfma_f32_16x16x32_bf16(afc, bf0[3], acc[r][3], 0, 0, 0);
      afc = nx;
    }
    __builtin_amdgcn_s_setprio(0);
    // bf0 dead until next phase: reload with (s+1, chunk0). ~1-phase cover.
#pragma unroll
    for (int ni = 0; ni < 4; ++ni) bf0[ni] = wq0[(ni << 6) + lane];
    // ---- chunk1 substeps
    __builtin_amdgcn_s_setprio(1);
#pragma unroll
    for (int r = 0; r < 5; ++r) {
      int na;
      if (r < 4) {
        na = ao[r + 1] + 64;
      } else {
        // advance shift state to s+1 (afc for (s,c1,r4) already in register)
#pragma unroll
        for (int rr = 0; rr < 5; ++rr) {
          bool w = (u[rr] == 24);
          u[rr]  = w ? 0 : u[rr] + 1;
          ao[rr] += w ? -(24 * ASTRIDE) : ASTRIDE;
        }
        na = ao[0];                    // frag(s+1, chunk0, r0)
      }
      s16x8 nx = *(const s16x8*)(Ash + na);
      acc[r][0] = __builtin_amdgcn_mfma_f32_16x16x32_bf16(afc, bf1[0], acc[r][0], 0, 0, 0);
      acc[r][1] = __builtin_amdgcn_mfma_f32_16x16x32_bf16(afc, bf1[1], acc[r][1], 0, 0, 0);
      acc[r][2] = __builtin_amdgcn_mfma_f32_16x16x32_bf16(afc, bf1[2], acc[r][2], 0, 0, 0);
      acc[r][3] = __builtin_amdgcn_mfma_f32_16x16x32_bf16(afc, bf1[3], acc[r][3], 0, 0, 0);
      afc = nx;
    }
    __builtin_amdgcn_s_setprio(0);
#pragma unroll
    for (int ni = 0; ni < 4; ++ni) bf1[ni] = wq1[(ni << 6) + lane];
  }

  // ---- per-channel sum/sumsq from registers (valid rows only)
  float s1v[4] = {0.f, 0.f, 0.f, 0.f}, s2v[4] = {0.f, 0.f, 0.f, 0.f};
#pragma unroll
  for (int r = 0; r < 5; ++r) {
#pragma unroll
    for (int qq = 0; qq < 4; ++qq) {
      int orow = ((wid * 5 + r) << 4) + (lk << 2) + qq;  // C/D: row=(l>>4)*4+reg
      if (orow < validRows) {
#pragma unroll
        for (int ct = 0; ct < 4; ++ct) {
          float val = acc[r][ct][qq];
          s1v[ct] += val;
          s2v[ct] += val * val;
        }
      }
    }
  }
#pragma unroll
  for (int ct = 0; ct < 4; ++ct) {
    float a = s1v[ct], b = s2v[ct];
    a += __shfl_xor(a, 16); a += __shfl_xor(a, 32);
    b += __shfl_xor(b, 16); b += __shfl_xor(b, 32);
    if (lane < 16) {
      int base = ((((wid << 2) + ct) << 4) + l15) * 2;
      red2[base]     = a;
      red2[base + 1] = b;
    }
  }

  // ---- epilogue: 4 o-quarters through LDS transpose, coalesced f4 stores
  float* T = (float*)Ash;
  float* outb = out + n * 480000 + tb * 400;   // + o*7500 + row
  for (int qt = 0; qt < 4; ++qt) {
    __syncthreads();   // qt=0: K-loop Ash reads + red2 writes done; else T reads
    // write acc[.][qt] -> T[o_local][row]
#pragma unroll
    for (int r = 0; r < 5; ++r) {
      int row0 = wid * 80 + r * 16 + (lk << 2);
      *(f32x4*)&T[l15 * TSTR + row0] = acc[r][qt];
    }
    __syncthreads();
    if (qt == 0 && tid < 128) {   // deterministic partial reduction (reads red2)
      int o = tid >> 1, m = tid & 1;
      int ct = o >> 4, ol = o & 15;
      float sres = 0.f;
#pragma unroll
      for (int w = 0; w < 5; ++w) sres += red2[((((w << 2) + ct) << 4) + ol) * 2 + m];
      int bl = blockIdx.y * 64 + blockIdx.x;
      partials[bl * 128 + m * 64 + o] = sres;
    }
    // read T + coalesced global f4 stores: 16 o x 100 f4-rows
#pragma unroll
    for (int i = 0; i < 5; ++i) {
      int idx = tid + i * 320;
      int ol  = idx / 100;
      int r4  = idx - ol * 100;
      if ((r4 << 2) < validRows) {
        float4 v = *(float4*)&T[ol * TSTR + (r4 << 2)];
        *(float4*)&outb[((qt << 4) + ol) * 7500 + (r4 << 2)] = v;
      }
    }
  }
}

// --- P2: reduce per-block partials -> per-channel scale/shift --------------
__global__ void finalize_kernel(const float* __restrict__ part,
                                const float* __restrict__ gamma,
                                const float* __restrict__ beta,
                                float* __restrict__ scsh) {
  __shared__ float sm[512];
  int o = blockIdx.x;            // 64 blocks, one channel each
  int tid = threadIdx.x;         // 256 threads
  float s1 = 0.f, s2 = 0.f;
  for (int b = tid; b < 1216; b += 256) {
    s1 += part[b * 128 + o];
    s2 += part[b * 128 + 64 + o];
  }
  sm[tid] = s1; sm[256 + tid] = s2;
  __syncthreads();
  for (int st = 128; st >= 1; st >>= 1) {
    if (tid < st) { sm[tid] += sm[tid + st]; sm[256 + tid] += sm[256 + tid + st]; }
    __syncthreads();
  }
  if (tid == 0) {
    const float inv = 1.0f / 480000.0f;
    float mean = sm[0] * inv;
    float var  = sm[256] * inv - mean * mean;
    float sc = gamma[o] * rsqrtf(var + 1e-5f);
    float sh = beta[o] - mean * sc;
    scsh[o]      = sc;
    scsh[64 + o] = sh;
  }
}

// --- P3: in-place BN-apply + ReLU, float4 ----------------------------------
__global__ void bn_relu_kernel(float4* __restrict__ out, const float* __restrict__ scsh) {
  int i = blockIdx.x * blockDim.x + threadIdx.x;
  const int total = 7680000;        // 30.72M / 4 ; 7500%4==0 so o uniform per f4
  int stride = gridDim.x * blockDim.x;
  for (; i < total; i += stride) {
    int o = (i / 1875) & 63;
    float sc = scsh[o], sh = scsh[64 + o];
    float4 v = out[i];
    v.x = fmaxf(fmaf(v.x, sc, sh), 0.f);
    v.y = fmaxf(fmaf(v.y, sc, sh), 0.f);
    v.z = fmaxf(fmaf(v.z, sc, sh), 0.f);
    v.w = fmaxf(fmaf(v.w, sc, sh), 0.f);
    out[i] = v;
  }
}

// ---------------------------------------------------------------------------
extern "C" void kernel_launch(void* const* d_in, const int* in_sizes, int n_in,
                              void* d_out, int out_size, void* d_ws, size_t ws_size,
                              hipStream_t stream) {
  const float* x     = (const float*)d_in[0];
  const float* W     = (const float*)d_in[1];
  // d_in[2] = b : cancels under batch-norm, unused.
  const float* gamma = (const float*)d_in[3];
  const float* beta  = (const float*)d_in[4];
  float* out = (float*)d_out;

  char* ws = (char*)d_ws;
  s16x8* Wg       = (s16x8*)ws;                       // 204,800 B
  float* partials = (float*)(ws + 204800);            // 1216*128*4 = 622,592 B
  float* scsh     = (float*)(ws + 204800 + 622592);   // 512 B

  pack_w_kernel<<<dim3(50), dim3(256), 0, stream>>>(W, Wg);
  tap_mm_kernel<<<dim3(64, TB_), dim3(NTHR_), 0, stream>>>(x, Wg, out, partials);
  finalize_kernel<<<dim3(64), dim3(256), 0, stream>>>(partials, gamma, beta, scsh);
  bn_relu_kernel<<<dim3(2048), dim3(256), 0, stream>>>((float4*)out, scsh);
}

// Round 9
// 208.011 us; speedup vs baseline: 10.7832x; 1.0219x over previous
//
#include <hip/hip_runtime.h>

// ---------------------------------------------------------------------------
// unit_gcn: out[n,o,t,v] = BN+ReLU of  sum_{s=0..24} Ws[s] @_c x[n,:,t,(v+s)%25]
//   Ws[0] = sum_i W[i,:,:,0];  Ws[s] = W[s-1,:,:,1]  (s>=1); bias cancels in BN.
// N=64, C=64, T=300, V=25, O=64.  x fp32 -> bf16 MFMA (16x16x32), fp32 accum.
// v6 (R9): depth-5 A-fragment ring (read issued 5 substeps = ~100cyc before
// use -> counted lgkmcnt, no per-substep drain); B ping-pong 2 phases deep;
// ASTRIDE 144 (bank stride 4 -> free 2-way); no setprio.
// ---------------------------------------------------------------------------

typedef short  s16x8 __attribute__((ext_vector_type(8)));
typedef float  f32x4 __attribute__((ext_vector_type(4)));

#define T_      300
#define TB_     19          // ceil(300/16) t-blocks
#define NTHR_   320         // 5 waves per block
#define ASTR    144         // A-slab row stride bytes (64c*2B + 16 pad; 16B-aligned)
#define TSTR    404         // epilogue transpose stride (f32)

__device__ __forceinline__ unsigned short f2bf(float f) {
  unsigned u = __builtin_bit_cast(unsigned, f);
  return (unsigned short)((u + 0x7FFFu + ((u >> 16) & 1u)) >> 16);
}

// --- P0: pack Ws into MFMA B-fragment layout (s-major: q = s*2 + chunk) ----
// Wg entry idx = ((s*2+chunk)*4 + ni)*64 + lane ; 8 bf16 per entry:
//   elem j = Ws[s][ o = ni*16 + (lane&15) ][ c = chunk*32 + (lane>>4)*8 + j ]
__global__ void pack_w_kernel(const float* __restrict__ W, s16x8* __restrict__ Wg) {
  int idx = blockIdx.x * 256 + threadIdx.x;
  if (idx >= 12800) return;
  int lane  = idx & 63;
  int ni    = (idx >> 6) & 3;
  int chunk = (idx >> 8) & 1;
  int s     = idx >> 9;
  int o     = (ni << 4) + (lane & 15);
  int cbase = (chunk << 5) + ((lane >> 4) << 3);
  s16x8 h;
#pragma unroll
  for (int j = 0; j < 8; ++j) {
    int c = cbase + j;
    float val;
    if (s == 0) {
      val = 0.f;
      for (int i = 0; i < 24; ++i) val += W[((i * 64 + o) * 64 + c) * 2];
    } else {
      val = W[(((s - 1) * 64 + o) * 64 + c) * 2 + 1];
    }
    h[j] = (short)f2bf(val);
  }
  Wg[idx] = h;
}

// 4 MFMAs: acc[J][0..3] += SR x Q0..Q3   (J is a literal)
#define MF(J, Q0, Q1, Q2, Q3, SR)                                               \
  acc[J][0] = __builtin_amdgcn_mfma_f32_16x16x32_bf16(SR, Q0, acc[J][0], 0, 0, 0); \
  acc[J][1] = __builtin_amdgcn_mfma_f32_16x16x32_bf16(SR, Q1, acc[J][1], 0, 0, 0); \
  acc[J][2] = __builtin_amdgcn_mfma_f32_16x16x32_bf16(SR, Q2, acc[J][2], 0, 0, 0); \
  acc[J][3] = __builtin_amdgcn_mfma_f32_16x16x32_bf16(SR, Q3, acc[J][3], 0, 0, 0);

// advance row-tile J's shift state (period 25)
#define ADV(J)                                                                  \
  { bool w_ = (u[J] == 24); u[J] = w_ ? 0 : u[J] + 1;                           \
    ao[J] += w_ ? -(24 * ASTR) : ASTR; }

// One full shift-phase (10 substeps, 40 MFMA). On entry S0..S4 = chunk0 frags
// of this shift (read 5 substeps ago). Substep j consumes S_j and issues the
// read for substep j+5 (chunk1 same shift, then next shift's chunk0).
// B-set (8 frags) is consumed this phase and reloaded with shift SN (= s+2).
#define PHASE(BA0, BA1, BA2, BA3, BA4, BA5, BA6, BA7, SN)                       \
  {                                                                             \
    const s16x8* wq_ = Wg + (SN) * 512;                                         \
    MF(0, BA0, BA1, BA2, BA3, S0) S0 = *(const s16x8*)(Ash + ao[0] + 64);       \
    MF(1, BA0, BA1, BA2, BA3, S1) S1 = *(const s16x8*)(Ash + ao[1] + 64);       \
    MF(2, BA0, BA1, BA2, BA3, S2) S2 = *(const s16x8*)(Ash + ao[2] + 64);       \
    MF(3, BA0, BA1, BA2, BA3, S3) S3 = *(const s16x8*)(Ash + ao[3] + 64);       \
    MF(4, BA0, BA1, BA2, BA3, S4) S4 = *(const s16x8*)(Ash + ao[4] + 64);       \
    BA0 = wq_[lane];       BA1 = wq_[64 + lane];                                \
    BA2 = wq_[128 + lane]; BA3 = wq_[192 + lane];                               \
    ADV(0) MF(0, BA4, BA5, BA6, BA7, S0) S0 = *(const s16x8*)(Ash + ao[0]);     \
    ADV(1) MF(1, BA4, BA5, BA6, BA7, S1) S1 = *(const s16x8*)(Ash + ao[1]);     \
    ADV(2) MF(2, BA4, BA5, BA6, BA7, S2) S2 = *(const s16x8*)(Ash + ao[2]);     \
    ADV(3) MF(3, BA4, BA5, BA6, BA7, S3) S3 = *(const s16x8*)(Ash + ao[3]);     \
    ADV(4) MF(4, BA4, BA5, BA6, BA7, S4) S4 = *(const s16x8*)(Ash + ao[4]);     \
    BA4 = wq_[256 + lane]; BA5 = wq_[320 + lane];                               \
    BA6 = wq_[384 + lane]; BA7 = wq_[448 + lane];                               \
  }

// --- P1: main tap-GEMM -----------------------------------------------------
// grid (n=64, tb=19), 320 thr = 5 waves. Block: 400 (t,v)-rows x 64 o.
// A-slab [400][64c] bf16 stride 144B in LDS (staged once). Wave: 5 row-tiles
// x 4 col-tiles, acc 5x4 f32x4.
__global__ __launch_bounds__(NTHR_) void tap_mm_kernel(
    const float* __restrict__ x, const s16x8* __restrict__ Wg,
    float* __restrict__ out, float* __restrict__ partials) {
  __shared__ __align__(16) char Ash[57600];   // A-slab; epilogue T[16][404] f32
  __shared__ float red2[640];
  int n  = blockIdx.x;
  int tb = blockIdx.y;
  int t0 = tb * 16;
  int validRows = min(16, T_ - t0) * 25;
  int tid = threadIdx.x;
  const float* xn = x + n * 480000 + t0 * 25;

  int wid = tid >> 6, lane = tid & 63;
  int l15 = lane & 15, lk = lane >> 4;

  // ---- B prologue: shifts 0 and 1, both chunks (global, L2-hot; issue first)
  s16x8 bfA0 = Wg[lane],       bfA1 = Wg[64 + lane];
  s16x8 bfA2 = Wg[128 + lane], bfA3 = Wg[192 + lane];
  s16x8 bfA4 = Wg[256 + lane], bfA5 = Wg[320 + lane];
  s16x8 bfA6 = Wg[384 + lane], bfA7 = Wg[448 + lane];
  s16x8 bfB0 = Wg[512 + lane], bfB1 = Wg[576 + lane];
  s16x8 bfB2 = Wg[640 + lane], bfB3 = Wg[704 + lane];
  s16x8 bfB4 = Wg[768 + lane], bfB5 = Wg[832 + lane];
  s16x8 bfB6 = Wg[896 + lane], bfB7 = Wg[960 + lane];

  // ---- stage A (once, K=64): 3200 tasks {8 strided c-loads -> 16B ds_write}
#pragma unroll 5
  for (int it = 0; it < 10; ++it) {
    int id  = tid + it * NTHR_;        // g*400 + pos
    int pos = id % 400;                // t_local*25 + u (contiguous in x)
    int g   = id / 400;                // c-subgroup (8 c's)
    bool vld = pos < validRows;
    s16x8 h;
#pragma unroll
    for (int j = 0; j < 8; ++j) {
      float f = vld ? xn[((g << 3) + j) * 7500 + pos] : 0.f;
      h[j] = (short)f2bf(f);
    }
    *(s16x8*)(Ash + pos * ASTR + (g << 4)) = h;
  }

  int u[5], ao[5];                      // ao = srow*ASTR + lk*16 (chunk0 addr)
#pragma unroll
  for (int r = 0; r < 5; ++r) {
    int orow = ((wid * 5 + r) << 4) + l15;   // A-side row this lane feeds
    int tL = orow / 25;
    u[r]  = orow - tL * 25;                  // = v; cycles with s, period 25
    ao[r] = orow * ASTR + (lk << 4);
  }
  f32x4 acc[5][4];
#pragma unroll
  for (int r = 0; r < 5; ++r)
#pragma unroll
    for (int ct = 0; ct < 4; ++ct) acc[r][ct] = (f32x4){0.f, 0.f, 0.f, 0.f};

  __syncthreads();

  // ---- A-ring prologue: chunk0 frags of shift 0
  s16x8 S0 = *(const s16x8*)(Ash + ao[0]);
  s16x8 S1 = *(const s16x8*)(Ash + ao[1]);
  s16x8 S2 = *(const s16x8*)(Ash + ao[2]);
  s16x8 S3 = *(const s16x8*)(Ash + ao[3]);
  s16x8 S4 = *(const s16x8*)(Ash + ao[4]);

  // ---- 25 shift-phases: 12 x (A-parity, B-parity) + tail A
  for (int k = 0; k < 12; ++k) {
    int sA = 2 * k + 2;                           // bfA reload shift
    int sB = 2 * k + 3; sB -= (sB >= 25) ? 25 : 0; // bfB reload (k=11 -> dummy)
    PHASE(bfA0, bfA1, bfA2, bfA3, bfA4, bfA5, bfA6, bfA7, sA)
    PHASE(bfB0, bfB1, bfB2, bfB3, bfB4, bfB5, bfB6, bfB7, sB)
  }
  PHASE(bfA0, bfA1, bfA2, bfA3, bfA4, bfA5, bfA6, bfA7, 1)  // s=24; dummy reload

  // ---- per-channel sum/sumsq from registers (valid rows only)
  float s1v[4] = {0.f, 0.f, 0.f, 0.f}, s2v[4] = {0.f, 0.f, 0.f, 0.f};
#pragma unroll
  for (int r = 0; r < 5; ++r) {
#pragma unroll
    for (int qq = 0; qq < 4; ++qq) {
      int orow = ((wid * 5 + r) << 4) + (lk << 2) + qq;  // C/D: row=(l>>4)*4+reg
      if (orow < validRows) {
#pragma unroll
        for (int ct = 0; ct < 4; ++ct) {
          float val = acc[r][ct][qq];
          s1v[ct] += val;
          s2v[ct] += val * val;
        }
      }
    }
  }
#pragma unroll
  for (int ct = 0; ct < 4; ++ct) {
    float a = s1v[ct], b = s2v[ct];
    a += __shfl_xor(a, 16); a += __shfl_xor(a, 32);
    b += __shfl_xor(b, 16); b += __shfl_xor(b, 32);
    if (lane < 16) {
      int base = ((((wid << 2) + ct) << 4) + l15) * 2;
      red2[base]     = a;
      red2[base + 1] = b;
    }
  }

  // ---- epilogue: 4 o-quarters through LDS transpose, coalesced f4 stores
  float* T = (float*)Ash;
  float* outb = out + n * 480000 + tb * 400;   // + o*7500 + row
  for (int qt = 0; qt < 4; ++qt) {
    __syncthreads();   // qt=0: K-loop Ash reads + red2 writes done; else T reads
    // write acc[.][qt] -> T[o_local][row]
#pragma unroll
    for (int r = 0; r < 5; ++r) {
      int row0 = wid * 80 + r * 16 + (lk << 2);
      *(f32x4*)&T[l15 * TSTR + row0] = acc[r][qt];
    }
    __syncthreads();
    if (qt == 0 && tid < 128) {   // deterministic partial reduction (reads red2)
      int o = tid >> 1, m = tid & 1;
      int ct = o >> 4, ol = o & 15;
      float sres = 0.f;
#pragma unroll
      for (int w = 0; w < 5; ++w) sres += red2[((((w << 2) + ct) << 4) + ol) * 2 + m];
      int bl = blockIdx.y * 64 + blockIdx.x;
      partials[bl * 128 + m * 64 + o] = sres;
    }
    // read T + coalesced global f4 stores: 16 o x 100 f4-rows
#pragma unroll
    for (int i = 0; i < 5; ++i) {
      int idx = tid + i * 320;
      int ol  = idx / 100;
      int r4  = idx - ol * 100;
      if ((r4 << 2) < validRows) {
        float4 v = *(float4*)&T[ol * TSTR + (r4 << 2)];
        *(float4*)&outb[((qt << 4) + ol) * 7500 + (r4 << 2)] = v;
      }
    }
  }
}

// --- P2: reduce per-block partials -> per-channel scale/shift --------------
__global__ void finalize_kernel(const float* __restrict__ part,
                                const float* __restrict__ gamma,
                                const float* __restrict__ beta,
                                float* __restrict__ scsh) {
  __shared__ float sm[512];
  int o = blockIdx.x;            // 64 blocks, one channel each
  int tid = threadIdx.x;         // 256 threads
  float s1 = 0.f, s2 = 0.f;
  for (int b = tid; b < 1216; b += 256) {
    s1 += part[b * 128 + o];
    s2 += part[b * 128 + 64 + o];
  }
  sm[tid] = s1; sm[256 + tid] = s2;
  __syncthreads();
  for (int st = 128; st >= 1; st >>= 1) {
    if (tid < st) { sm[tid] += sm[tid + st]; sm[256 + tid] += sm[256 + tid + st]; }
    __syncthreads();
  }
  if (tid == 0) {
    const float inv = 1.0f / 480000.0f;
    float mean = sm[0] * inv;
    float var  = sm[256] * inv - mean * mean;
    float sc = gamma[o] * rsqrtf(var + 1e-5f);
    float sh = beta[o] - mean * sc;
    scsh[o]      = sc;
    scsh[64 + o] = sh;
  }
}

// --- P3: in-place BN-apply + ReLU, float4 ----------------------------------
__global__ void bn_relu_kernel(float4* __restrict__ out, const float* __restrict__ scsh) {
  int i = blockIdx.x * blockDim.x + threadIdx.x;
  const int total = 7680000;        // 30.72M / 4 ; 7500%4==0 so o uniform per f4
  int stride = gridDim.x * blockDim.x;
  for (; i < total; i += stride) {
    int o = (i / 1875) & 63;
    float sc = scsh[o], sh = scsh[64 + o];
    float4 v = out[i];
    v.x = fmaxf(fmaf(v.x, sc, sh), 0.f);
    v.y = fmaxf(fmaf(v.y, sc, sh), 0.f);
    v.z = fmaxf(fmaf(v.z, sc, sh), 0.f);
    v.w = fmaxf(fmaf(v.w, sc, sh), 0.f);
    out[i] = v;
  }
}

// ---------------------------------------------------------------------------
extern "C" void kernel_launch(void* const* d_in, const int* in_sizes, int n_in,
                              void* d_out, int out_size, void* d_ws, size_t ws_size,
                              hipStream_t stream) {
  const float* x     = (const float*)d_in[0];
  const float* W     = (const float*)d_in[1];
  // d_in[2] = b : cancels under batch-norm, unused.
  const float* gamma = (const float*)d_in[3];
  const float* beta  = (const float*)d_in[4];
  float* out = (float*)d_out;

  char* ws = (char*)d_ws;
  s16x8* Wg       = (s16x8*)ws;                       // 204,800 B
  float* partials = (float*)(ws + 204800);            // 1216*128*4 = 622,592 B
  float* scsh     = (float*)(ws + 204800 + 622592);   // 512 B

  pack_w_kernel<<<dim3(50), dim3(256), 0, stream>>>(W, Wg);
  tap_mm_kernel<<<dim3(64, TB_), dim3(NTHR_), 0, stream>>>(x, Wg, out, partials);
  finalize_kernel<<<dim3(64), dim3(256), 0, stream>>>(partials, gamma, beta, scsh);
  bn_relu_kernel<<<dim3(2048), dim3(256), 0, stream>>>((float4*)out, scsh);
}